// Round 2
// baseline (806.882 us; speedup 1.0000x reference)
//
#include <hip/hip_runtime.h>
#include <hip/hip_bf16.h>
#include <cstdint>

// Problem dims
#define N_TOK 8192   // B*T
#define D_IN  1024
#define DFF   4096
#define NE    8
#define DEPTH 3      // K-loop pipeline depth (LDS buffers)

typedef __bf16 bf16x8 __attribute__((ext_vector_type(8)));
typedef float  f32x4  __attribute__((ext_vector_type(4)));

// ---------- helpers ----------
__device__ __forceinline__ unsigned short f2bf(float f) {
  unsigned u = __float_as_uint(f);
  u += 0x7fffu + ((u >> 16) & 1u);   // RNE
  return (unsigned short)(u >> 16);
}

__device__ __forceinline__ void gll16(const void* g, void* l) {
  __builtin_amdgcn_global_load_lds(
      (__attribute__((address_space(1))) void*)g,
      (__attribute__((address_space(3))) void*)l, 16, 0, 0);
}

// ---------- gate: logits (fp64 acc) -> argmax -> bucketize; also x->bf16 ----------
__global__ __launch_bounds__(256) void gate_kernel(
    const float* __restrict__ x, const float* __restrict__ gW,
    const float* __restrict__ gb, unsigned short* __restrict__ xbf,
    int* __restrict__ counts, int* __restrict__ perm) {
  int wave = threadIdx.x >> 6, lane = threadIdx.x & 63;
  int n = blockIdx.x * 4 + wave;
  const float* xr = x + (size_t)n * D_IN;
  double acc[NE];
#pragma unroll
  for (int e = 0; e < NE; ++e) acc[e] = 0.0;
#pragma unroll
  for (int j = 0; j < 16; ++j) {
    int d = j * 64 + lane;
    float v = xr[d];
    xbf[(size_t)n * D_IN + d] = f2bf(v);
    float4 g0 = *(const float4*)(gW + (size_t)d * 8);
    float4 g1 = *(const float4*)(gW + (size_t)d * 8 + 4);
    acc[0] += (double)v * (double)g0.x;
    acc[1] += (double)v * (double)g0.y;
    acc[2] += (double)v * (double)g0.z;
    acc[3] += (double)v * (double)g0.w;
    acc[4] += (double)v * (double)g1.x;
    acc[5] += (double)v * (double)g1.y;
    acc[6] += (double)v * (double)g1.z;
    acc[7] += (double)v * (double)g1.w;
  }
#pragma unroll
  for (int m = 32; m >= 1; m >>= 1) {
#pragma unroll
    for (int e = 0; e < NE; ++e) acc[e] += __shfl_xor(acc[e], m);
  }
  if (lane == 0) {
    float best = (float)acc[0] + gb[0];
    int be = 0;
#pragma unroll
    for (int e = 1; e < NE; ++e) {
      float lv = (float)acc[e] + gb[e];
      if (lv > best) { best = lv; be = e; }   // strict > => first max (jnp.argmax)
    }
    int pos = atomicAdd(&counts[be], 1);
    perm[be * N_TOK + pos] = n;
  }
}

// ---------- plan: offsets + tile worklist ----------
__global__ void plan_kernel(int* __restrict__ hdr, int* __restrict__ tile_e,
                            int* __restrict__ tile_m) {
  if (threadIdx.x != 0 || blockIdx.x != 0) return;
  int off = 0;
  for (int e = 0; e < NE; ++e) { hdr[8 + e] = off; off += hdr[e]; }
  hdr[16] = off;
  int nt = 0;
  for (int e = 0; e < NE; ++e)
    for (int m0 = 0; m0 < hdr[e]; m0 += 128) { tile_e[nt] = e; tile_m[nt] = m0; ++nt; }
  hdr[17] = nt;
}

// ---------- transpose + fp32->bf16: src[e][R][C] -> dst[e][C][R] ----------
__global__ __launch_bounds__(256) void transpose_cvt(
    const float* __restrict__ src, unsigned short* __restrict__ dst,
    int R, int C, int tiles_r, int tiles_c) {
  __shared__ unsigned short tile[64][68];
  int tpe = tiles_r * tiles_c;
  int e = blockIdx.x / tpe;
  int t = blockIdx.x % tpe;
  int r0 = (t / tiles_c) * 64, c0 = (t % tiles_c) * 64;
  const float* s = src + (size_t)e * R * C;
  unsigned short* dp = dst + (size_t)e * R * C;
  int tr = threadIdx.x >> 4, tc = (threadIdx.x & 15) * 4;
#pragma unroll
  for (int p = 0; p < 4; ++p) {
    int row = r0 + tr + p * 16;
    const float4 v = *(const float4*)(s + (size_t)row * C + c0 + tc);
    tile[tc + 0][tr + p * 16] = f2bf(v.x);
    tile[tc + 1][tr + p * 16] = f2bf(v.y);
    tile[tc + 2][tr + p * 16] = f2bf(v.z);
    tile[tc + 3][tr + p * 16] = f2bf(v.w);
  }
  __syncthreads();
#pragma unroll
  for (int p = 0; p < 4; ++p) {
    int cr = tr + p * 16;
    ushort4 o;
    o.x = tile[cr][tc + 0];
    o.y = tile[cr][tc + 1];
    o.z = tile[cr][tc + 2];
    o.w = tile[cr][tc + 3];
    *(ushort4*)(dp + (size_t)(c0 + cr) * R + r0 + tc) = o;
  }
}

// ---------- GEMM1: H = gelu(Xg @ W1 + b1), pipelined K-loop ----------
__global__ __launch_bounds__(256) void gemm1(
    const unsigned short* __restrict__ xbf, const unsigned short* __restrict__ w1t,
    const float* __restrict__ b1, const int* __restrict__ hdr,
    const int* __restrict__ tile_e, const int* __restrict__ tile_m,
    const int* __restrict__ perm, unsigned short* __restrict__ H) {
  int wi = blockIdx.x >> 5;            // 32 n-tiles (DFF/128)
  if (wi >= hdr[17]) return;
  int nt = blockIdx.x & 31;
  int e = tile_e[wi];
  int m0 = tile_m[wi];
  int Me = hdr[e];
  int hbase = hdr[8 + e];
  int n0 = nt * 128;

  __shared__ __align__(16) char Asm[DEPTH * 8192];
  __shared__ __align__(16) char Bsm[DEPTH * 8192];

  int tid = threadIdx.x, wave = tid >> 6, lane = tid & 63;
  int wm = wave >> 1, wn = wave & 1;
  int kq = lane >> 4, m = lane & 15;

  const char* aptr[2];
  const char* bptr[2];
  int off[2];
#pragma unroll
  for (int s = 0; s < 2; ++s) {
    int g = wave * 2 + s;
    int r = m0 + g * 16 + m;
    if (r >= Me) r = Me - 1;
    int token = perm[e * N_TOK + r];
    aptr[s] = (const char*)xbf + (size_t)token * (D_IN * 2) + kq * 16;
    int f = n0 + g * 16 + m;
    bptr[s] = (const char*)w1t + ((size_t)e * DFF + f) * (D_IN * 2) + kq * 16;
    off[s] = g * 1024 + lane * 16;
  }

  const int NITER = D_IN / 32;  // 32
#pragma unroll
  for (int p = 0; p < DEPTH; ++p) {
    gll16(aptr[0] + p * 64, Asm + p * 8192 + off[0]);
    gll16(aptr[1] + p * 64, Asm + p * 8192 + off[1]);
    gll16(bptr[0] + p * 64, Bsm + p * 8192 + off[0]);
    gll16(bptr[1] + p * 64, Bsm + p * 8192 + off[1]);
  }

  f32x4 acc[4][4];
#pragma unroll
  for (int i = 0; i < 4; ++i)
#pragma unroll
    for (int j = 0; j < 4; ++j) { f32x4 z = {0.f, 0.f, 0.f, 0.f}; acc[i][j] = z; }

  int cur = 0;
  for (int kk = 0; kk < NITER; ++kk) {
    asm volatile("s_waitcnt vmcnt(8)" ::: "memory");   // iter kk's 4 loads landed; 8 newer stay in flight
    __builtin_amdgcn_s_barrier();
    const char* ab = Asm + cur * 8192;
    const char* bb = Bsm + cur * 8192;
    bf16x8 af[4], bfv[4];
#pragma unroll
    for (int i = 0; i < 4; ++i)
      af[i] = *(const bf16x8*)(ab + (wm * 4 + i) * 1024 + lane * 16);
#pragma unroll
    for (int j = 0; j < 4; ++j)
      bfv[j] = *(const bf16x8*)(bb + (wn * 4 + j) * 1024 + lane * 16);
    asm volatile("s_waitcnt lgkmcnt(0)" ::: "memory"); // frags in regs before buffer recycled
    __builtin_amdgcn_s_barrier();
    int nx = kk + DEPTH;
    if (nx > NITER - 1) nx = NITER - 1;                // dummy tail loads keep vmcnt uniform
    char* ad = Asm + cur * 8192;
    char* bd = Bsm + cur * 8192;
    gll16(aptr[0] + nx * 64, ad + off[0]);
    gll16(aptr[1] + nx * 64, ad + off[1]);
    gll16(bptr[0] + nx * 64, bd + off[0]);
    gll16(bptr[1] + nx * 64, bd + off[1]);
#pragma unroll
    for (int i = 0; i < 4; ++i)
#pragma unroll
      for (int j = 0; j < 4; ++j)
        acc[i][j] = __builtin_amdgcn_mfma_f32_16x16x32_bf16(af[i], bfv[j], acc[i][j], 0, 0, 0);
    cur = (cur == DEPTH - 1) ? 0 : cur + 1;
  }

  int quad = lane >> 4, col_l = lane & 15;
#pragma unroll
  for (int i = 0; i < 4; ++i) {
    int rbase = m0 + wm * 64 + i * 16 + quad * 4;
#pragma unroll
    for (int j = 0; j < 4; ++j) {
      int f = n0 + wn * 64 + j * 16 + col_l;
      float bb = b1[(size_t)e * DFF + f];
#pragma unroll
      for (int r = 0; r < 4; ++r) {
        int rr = rbase + r;
        if (rr < Me) {
          float v = acc[i][j][r] + bb;
          v = 0.5f * v * (1.0f + erff(v * 0.70710678118654752f));  // exact gelu
          H[(size_t)(hbase + rr) * DFF + f] = f2bf(v);
        }
      }
    }
  }
}

// ---------- GEMM2: out[token] = H @ W2 + b2, pipelined K-loop ----------
__global__ __launch_bounds__(256) void gemm2(
    const unsigned short* __restrict__ H, const unsigned short* __restrict__ w2t,
    const float* __restrict__ b2, const int* __restrict__ hdr,
    const int* __restrict__ tile_e, const int* __restrict__ tile_m,
    const int* __restrict__ perm, float* __restrict__ out) {
  int wi = blockIdx.x >> 3;            // 8 n-tiles (D/128)
  if (wi >= hdr[17]) return;
  int nt = blockIdx.x & 7;
  int e = tile_e[wi];
  int m0 = tile_m[wi];
  int Me = hdr[e];
  int hbase = hdr[8 + e];
  int n0 = nt * 128;

  __shared__ __align__(16) char Asm[DEPTH * 8192];
  __shared__ __align__(16) char Bsm[DEPTH * 8192];

  int tid = threadIdx.x, wave = tid >> 6, lane = tid & 63;
  int wm = wave >> 1, wn = wave & 1;
  int kq = lane >> 4, m = lane & 15;

  const char* aptr[2];
  const char* bptr[2];
  int off[2];
#pragma unroll
  for (int s = 0; s < 2; ++s) {
    int g = wave * 2 + s;
    int r = m0 + g * 16 + m;
    if (r >= Me) r = Me - 1;
    aptr[s] = (const char*)H + (size_t)(hbase + r) * (DFF * 2) + kq * 16;
    int d = n0 + g * 16 + m;
    bptr[s] = (const char*)w2t + ((size_t)e * D_IN + d) * (DFF * 2) + kq * 16;
    off[s] = g * 1024 + lane * 16;
  }

  const int NITER = DFF / 32;  // 128
#pragma unroll
  for (int p = 0; p < DEPTH; ++p) {
    gll16(aptr[0] + p * 64, Asm + p * 8192 + off[0]);
    gll16(aptr[1] + p * 64, Asm + p * 8192 + off[1]);
    gll16(bptr[0] + p * 64, Bsm + p * 8192 + off[0]);
    gll16(bptr[1] + p * 64, Bsm + p * 8192 + off[1]);
  }

  f32x4 acc[4][4];
#pragma unroll
  for (int i = 0; i < 4; ++i)
#pragma unroll
    for (int j = 0; j < 4; ++j) { f32x4 z = {0.f, 0.f, 0.f, 0.f}; acc[i][j] = z; }

  int cur = 0;
  for (int kk = 0; kk < NITER; ++kk) {
    asm volatile("s_waitcnt vmcnt(8)" ::: "memory");
    __builtin_amdgcn_s_barrier();
    const char* ab = Asm + cur * 8192;
    const char* bb = Bsm + cur * 8192;
    bf16x8 af[4], bfv[4];
#pragma unroll
    for (int i = 0; i < 4; ++i)
      af[i] = *(const bf16x8*)(ab + (wm * 4 + i) * 1024 + lane * 16);
#pragma unroll
    for (int j = 0; j < 4; ++j)
      bfv[j] = *(const bf16x8*)(bb + (wn * 4 + j) * 1024 + lane * 16);
    asm volatile("s_waitcnt lgkmcnt(0)" ::: "memory");
    __builtin_amdgcn_s_barrier();
    int nx = kk + DEPTH;
    if (nx > NITER - 1) nx = NITER - 1;
    char* ad = Asm + cur * 8192;
    char* bd = Bsm + cur * 8192;
    gll16(aptr[0] + nx * 64, ad + off[0]);
    gll16(aptr[1] + nx * 64, ad + off[1]);
    gll16(bptr[0] + nx * 64, bd + off[0]);
    gll16(bptr[1] + nx * 64, bd + off[1]);
#pragma unroll
    for (int i = 0; i < 4; ++i)
#pragma unroll
      for (int j = 0; j < 4; ++j)
        acc[i][j] = __builtin_amdgcn_mfma_f32_16x16x32_bf16(af[i], bfv[j], acc[i][j], 0, 0, 0);
    cur = (cur == DEPTH - 1) ? 0 : cur + 1;
  }

  int quad = lane >> 4, col_l = lane & 15;
#pragma unroll
  for (int i = 0; i < 4; ++i) {
    int rbase = m0 + wm * 64 + i * 16 + quad * 4;
#pragma unroll
    for (int j = 0; j < 4; ++j) {
      int col = n0 + wn * 64 + j * 16 + col_l;
      float bb = b2[(size_t)e * D_IN + col];
#pragma unroll
      for (int r = 0; r < 4; ++r) {
        int rr = rbase + r;
        if (rr < Me) {
          int token = perm[e * N_TOK + rr];
          out[(size_t)token * D_IN + col] = acc[i][j][r] + bb;
        }
      }
    }
  }
}

// ---------- launch ----------
extern "C" void kernel_launch(void* const* d_in, const int* in_sizes, int n_in,
                              void* d_out, int out_size, void* d_ws, size_t ws_size,
                              hipStream_t stream) {
  const float* x  = (const float*)d_in[0];
  const float* gW = (const float*)d_in[1];
  const float* gb = (const float*)d_in[2];
  const float* W1 = (const float*)d_in[3];
  const float* b1 = (const float*)d_in[4];
  const float* W2 = (const float*)d_in[5];
  const float* b2 = (const float*)d_in[6];
  float* out = (float*)d_out;

  char* ws = (char*)d_ws;
  int* hdr    = (int*)ws;                    // [0..7] counts, [8..16] offsets, [17] numTiles
  int* tile_e = (int*)(ws + 256);
  int* tile_m = (int*)(ws + 1024);
  int* perm   = (int*)(ws + 4096);                       // NE*N_TOK ints = 256KB
  unsigned short* xbf = (unsigned short*)(ws + 266240);  // 16 MB
  unsigned short* WT  = (unsigned short*)(ws + 17043456); // 64 MB (W1T, then W2T)
  unsigned short* H   = (unsigned short*)(ws + 84152320); // 64 MB
  // total ws use: ~151.3 MB

  hipMemsetAsync(hdr, 0, 256, stream);
  gate_kernel<<<N_TOK / 4, 256, 0, stream>>>(x, gW, gb, xbf, hdr, perm);
  plan_kernel<<<1, 64, 0, stream>>>(hdr, tile_e, tile_m);
  transpose_cvt<<<NE * (D_IN / 64) * (DFF / 64), 256, 0, stream>>>(W1, WT, D_IN, DFF,
                                                                   D_IN / 64, DFF / 64);
  gemm1<<<71 * 32, 256, 0, stream>>>(xbf, WT, b1, hdr, tile_e, tile_m, perm, H);
  transpose_cvt<<<NE * (DFF / 64) * (D_IN / 64), 256, 0, stream>>>(W2, WT, DFF, D_IN,
                                                                   DFF / 64, D_IN / 64);
  gemm2<<<71 * 8, 256, 0, stream>>>(H, WT, b2, hdr, tile_e, tile_m, perm, out);
}

// Round 3
// 651.720 us; speedup vs baseline: 1.2381x; 1.2381x over previous
//
#include <hip/hip_runtime.h>
#include <hip/hip_bf16.h>
#include <cstdint>

// Problem dims
#define N_TOK 8192   // B*T
#define D_IN  1024
#define DFF   4096
#define NE    8
#define DEPTH 3      // K-loop pipeline depth (LDS buffers)

typedef __bf16 bf16x8 __attribute__((ext_vector_type(8)));
typedef float  f32x4  __attribute__((ext_vector_type(4)));

// ---------- helpers ----------
__device__ __forceinline__ unsigned short f2bf(float f) {
  unsigned u = __float_as_uint(f);
  u += 0x7fffu + ((u >> 16) & 1u);   // RNE
  return (unsigned short)(u >> 16);
}

__device__ __forceinline__ void gll16(const void* g, void* l) {
  __builtin_amdgcn_global_load_lds(
      (__attribute__((address_space(1))) void*)g,
      (__attribute__((address_space(3))) void*)l, 16, 0, 0);
}

// ---------- gate: logits (fp64 acc) -> argmax -> bucketize; also x->bf16 ----------
__global__ __launch_bounds__(256) void gate_kernel(
    const float* __restrict__ x, const float* __restrict__ gW,
    const float* __restrict__ gb, unsigned short* __restrict__ xbf,
    int* __restrict__ counts, int* __restrict__ perm) {
  int wave = threadIdx.x >> 6, lane = threadIdx.x & 63;
  int n = blockIdx.x * 4 + wave;
  const float* xr = x + (size_t)n * D_IN;
  double acc[NE];
#pragma unroll
  for (int e = 0; e < NE; ++e) acc[e] = 0.0;
#pragma unroll
  for (int j = 0; j < 16; ++j) {
    int d = j * 64 + lane;
    float v = xr[d];
    xbf[(size_t)n * D_IN + d] = f2bf(v);
    float4 g0 = *(const float4*)(gW + (size_t)d * 8);
    float4 g1 = *(const float4*)(gW + (size_t)d * 8 + 4);
    acc[0] += (double)v * (double)g0.x;
    acc[1] += (double)v * (double)g0.y;
    acc[2] += (double)v * (double)g0.z;
    acc[3] += (double)v * (double)g0.w;
    acc[4] += (double)v * (double)g1.x;
    acc[5] += (double)v * (double)g1.y;
    acc[6] += (double)v * (double)g1.z;
    acc[7] += (double)v * (double)g1.w;
  }
#pragma unroll
  for (int m = 32; m >= 1; m >>= 1) {
#pragma unroll
    for (int e = 0; e < NE; ++e) acc[e] += __shfl_xor(acc[e], m);
  }
  if (lane == 0) {
    float best = (float)acc[0] + gb[0];
    int be = 0;
#pragma unroll
    for (int e = 1; e < NE; ++e) {
      float lv = (float)acc[e] + gb[e];
      if (lv > best) { best = lv; be = e; }   // strict > => first max (jnp.argmax)
    }
    int pos = atomicAdd(&counts[be], 1);
    perm[be * N_TOK + pos] = n;
  }
}

// ---------- plan: offsets + both tile worklists + sub0 map ----------
__global__ void plan_kernel(int* __restrict__ hdr, int* __restrict__ tile_e,
                            int* __restrict__ tile_m, int* __restrict__ sub0,
                            int* __restrict__ tile_e2, int* __restrict__ tile_m2) {
  if (threadIdx.x != 0 || blockIdx.x != 0) return;
  int off = 0;
  for (int e = 0; e < NE; ++e) { hdr[8 + e] = off; off += hdr[e]; }
  hdr[16] = off;
  int n1 = 0, n2 = 0;
  for (int e = 0; e < NE; ++e) {
    int Me = hdr[e];
    int base2 = n2;
    for (int m2 = 0; m2 < Me; m2 += 64) { tile_e2[n2] = e; tile_m2[n2] = m2; ++n2; }
    for (int m0 = 0; m0 < Me; m0 += 128) {
      tile_e[n1] = e; tile_m[n1] = m0; sub0[n1] = base2 + (m0 >> 6); ++n1;
    }
  }
  hdr[17] = n1;
  hdr[18] = n2;
}

// ---------- A pack: gather perm rows of xbf into gemm1 LDS-fragment order ----------
// Apack chunk(wi,kk,g,lane=kq*16+m) holds row (g*16+m) of tile wi, k=kk*32+kq*8..+8
__global__ __launch_bounds__(256) void apack_kernel(
    const unsigned short* __restrict__ xbf, const int* __restrict__ hdr,
    const int* __restrict__ tile_e, const int* __restrict__ tile_m,
    const int* __restrict__ perm, unsigned short* __restrict__ Apack) {
  int wi = blockIdx.x >> 2;
  if (wi >= hdr[17]) return;
  int q = blockIdx.x & 3;
  int e = tile_e[wi], m0 = tile_m[wi], Me = hdr[e];
  int wave = threadIdx.x >> 6, lane = threadIdx.x & 63;
  int kq = lane >> 4, m = lane & 15;
#pragma unroll
  for (int s = 0; s < 2; ++s) {
    int g = wave * 2 + s;
    int r = m0 + g * 16 + m;
    if (r >= Me) r = Me - 1;
    int token = perm[e * N_TOK + r];
    const char* src = (const char*)xbf + (size_t)token * 2048 + kq * 16;
    char* dst = (char*)Apack + (size_t)wi * 32 * 8192 + g * 1024 + lane * 16;
    for (int kk = q * 8; kk < q * 8 + 8; ++kk)
      *(int4*)(dst + (size_t)kk * 8192) = *(const int4*)(src + kk * 64);
  }
}

// ---------- W pack: src[e][R(k)][C(f)] fp32 -> packed bf16 tiles in LDS-frag order ----------
// chunk off = (((e*(C>>7)+nt)*(R>>5)+kk)*8+gg)*1024 + (kq*16+mm)*16 ; f=nt*128+gg*16+mm, k=kk*32+kq*8..+8
__global__ __launch_bounds__(256) void wpack_kernel(
    const float* __restrict__ src, unsigned short* __restrict__ dst,
    int R, int C, int tiles_r, int tiles_c) {
  __shared__ unsigned short tile[64][72];   // [f-local][k-local], 16B-aligned rows
  int tpe = tiles_r * tiles_c;
  int e = blockIdx.x / tpe;
  int t = blockIdx.x % tpe;
  int r0 = (t / tiles_c) * 64, c0 = (t % tiles_c) * 64;  // r0: k base, c0: f base
  const float* s = src + (size_t)e * R * C;
  int tr = threadIdx.x >> 4, tc = (threadIdx.x & 15) * 4;
#pragma unroll
  for (int p = 0; p < 4; ++p) {
    int row = r0 + tr + p * 16;  // k
    const float4 v = *(const float4*)(s + (size_t)row * C + c0 + tc);
    tile[tc + 0][tr + p * 16] = f2bf(v.x);
    tile[tc + 1][tr + p * 16] = f2bf(v.y);
    tile[tc + 2][tr + p * 16] = f2bf(v.z);
    tile[tc + 3][tr + p * 16] = f2bf(v.w);
  }
  __syncthreads();
  int nkk = R >> 5, ntc = C >> 7;
#pragma unroll
  for (int u = 0; u < 2; ++u) {
    int c = u * 256 + threadIdx.x;        // 0..511 chunks of 16B
    int kk_l = c >> 8, gg_l = (c >> 6) & 3, kq = (c >> 4) & 3, mm = c & 15;
    int fl = gg_l * 16 + mm;
    int kl = kk_l * 32 + kq * 8;
    int4 val = *(const int4*)&tile[fl][kl];
    int f = c0 + fl;
    int nt = f >> 7, gg = (f >> 4) & 7;
    int kk = (r0 >> 5) + kk_l;
    size_t off = ((((size_t)e * ntc + nt) * nkk + kk) * 8 + gg) * 1024 + (kq * 16 + mm) * 16;
    *(int4*)((char*)dst + off) = val;
  }
}

// ---------- GEMM1: Hpack = pack(gelu(Xg @ W1 + b1)), pipelined, all-contiguous loads ----------
__global__ __launch_bounds__(256) void gemm1(
    const unsigned short* __restrict__ Apack, const unsigned short* __restrict__ Bpack1,
    const float* __restrict__ b1, const int* __restrict__ hdr,
    const int* __restrict__ tile_e, const int* __restrict__ tile_m,
    const int* __restrict__ sub0, unsigned short* __restrict__ Hpack) {
  int wi = blockIdx.x >> 5;            // 32 n-tiles (DFF/128)
  if (wi >= hdr[17]) return;
  int nt = blockIdx.x & 31;
  int e = tile_e[wi];
  int m0 = tile_m[wi];
  int Me = hdr[e];
  int n0 = nt * 128;

  __shared__ __align__(16) char smem[49152];
  char* Asm = smem;              // DEPTH x 8192
  char* Bsm = smem + 24576;      // DEPTH x 8192

  int tid = threadIdx.x, wave = tid >> 6, lane = tid & 63;
  int wm = wave >> 1, wn = wave & 1;

  const char* abase = (const char*)Apack + (size_t)wi * 32 * 8192;
  const char* bbase = (const char*)Bpack1 + (size_t)(e * 32 + nt) * 32 * 8192;
  int off0 = (wave * 2 + 0) * 1024 + lane * 16;
  int off1 = (wave * 2 + 1) * 1024 + lane * 16;

  const int NITER = D_IN / 32;  // 32
#pragma unroll
  for (int p = 0; p < DEPTH; ++p) {
    gll16(abase + (size_t)p * 8192 + off0, Asm + p * 8192 + off0);
    gll16(abase + (size_t)p * 8192 + off1, Asm + p * 8192 + off1);
    gll16(bbase + (size_t)p * 8192 + off0, Bsm + p * 8192 + off0);
    gll16(bbase + (size_t)p * 8192 + off1, Bsm + p * 8192 + off1);
  }

  f32x4 acc[4][4];
#pragma unroll
  for (int i = 0; i < 4; ++i)
#pragma unroll
    for (int j = 0; j < 4; ++j) { f32x4 z = {0.f, 0.f, 0.f, 0.f}; acc[i][j] = z; }

  int cur = 0;
  for (int kk = 0; kk < NITER; ++kk) {
    asm volatile("s_waitcnt vmcnt(8)" ::: "memory");   // iter kk's 4 loads landed
    __builtin_amdgcn_s_barrier();
    const char* ab = Asm + cur * 8192;
    const char* bb = Bsm + cur * 8192;
    bf16x8 af[4], bfv[4];
#pragma unroll
    for (int i = 0; i < 4; ++i)
      af[i] = *(const bf16x8*)(ab + (wm * 4 + i) * 1024 + lane * 16);
#pragma unroll
    for (int j = 0; j < 4; ++j)
      bfv[j] = *(const bf16x8*)(bb + (wn * 4 + j) * 1024 + lane * 16);
    asm volatile("s_waitcnt lgkmcnt(0)" ::: "memory"); // frags in regs before recycle
    __builtin_amdgcn_s_barrier();
    int nx = kk + DEPTH;
    if (nx > NITER - 1) nx = NITER - 1;                // dummy tail keeps vmcnt uniform
    char* ad = Asm + cur * 8192;
    char* bd = Bsm + cur * 8192;
    gll16(abase + (size_t)nx * 8192 + off0, ad + off0);
    gll16(abase + (size_t)nx * 8192 + off1, ad + off1);
    gll16(bbase + (size_t)nx * 8192 + off0, bd + off0);
    gll16(bbase + (size_t)nx * 8192 + off1, bd + off1);
#pragma unroll
    for (int i = 0; i < 4; ++i)
#pragma unroll
      for (int j = 0; j < 4; ++j)
        acc[i][j] = __builtin_amdgcn_mfma_f32_16x16x32_bf16(af[i], bfv[j], acc[i][j], 0, 0, 0);
    cur = (cur == DEPTH - 1) ? 0 : cur + 1;
  }

  // ---- epilogue: gelu+bias -> LDS (row-major bf16) -> Hpack (gemm2 A-frag order) ----
  asm volatile("s_waitcnt vmcnt(0)" ::: "memory");  // drain dummies before LDS reuse
  __syncthreads();
  unsigned short* Cl = (unsigned short*)smem;       // 128x128 bf16 = 32 KB
  int quad = lane >> 4, col_l = lane & 15;
#pragma unroll
  for (int i = 0; i < 4; ++i) {
#pragma unroll
    for (int j = 0; j < 4; ++j) {
      int f = n0 + wn * 64 + j * 16 + col_l;
      float bb = b1[(size_t)e * DFF + f];
      int lc = wn * 64 + j * 16 + col_l;
#pragma unroll
      for (int r = 0; r < 4; ++r) {
        int lr = wm * 64 + i * 16 + quad * 4 + r;
        float v = acc[i][j][r] + bb;
        v = 0.5f * v * (1.0f + erff(v * 0.70710678118654752f));  // exact gelu
        Cl[lr * 128 + lc] = f2bf(v);
      }
    }
  }
  __syncthreads();
  int s0 = sub0[wi];
  bool hasB = (m0 + 64 < Me);
#pragma unroll
  for (int u = 0; u < 8; ++u) {
    int c = u * 256 + tid;            // 0..2047 chunks of 16B
    int lr = c >> 4, fc = c & 15;
    int sv = lr >> 6;
    if (sv == 1 && !hasB) continue;
    int4 val = *(const int4*)(Cl + lr * 128 + fc * 8);
    int wi2 = s0 + sv;
    int m2 = lr & 63;
    int gg = m2 >> 4, mm = m2 & 15;
    int kk2 = nt * 4 + (fc >> 2), kq2 = fc & 3;
    *(int4*)((char*)Hpack + ((size_t)wi2 * 128 + kk2) * 4096 + gg * 1024 + (kq2 * 16 + mm) * 16) = val;
  }
}

// ---------- GEMM2: out[token] = Hpack @ W2 + b2, BM=64, pipelined ----------
__global__ __launch_bounds__(256) void gemm2(
    const unsigned short* __restrict__ Hpack, const unsigned short* __restrict__ Bpack2,
    const float* __restrict__ b2, const int* __restrict__ hdr,
    const int* __restrict__ tile_e2, const int* __restrict__ tile_m2,
    const int* __restrict__ perm, float* __restrict__ out) {
  int wi = blockIdx.x >> 3;            // 8 n-tiles (D/128)
  if (wi >= hdr[18]) return;
  int nt = blockIdx.x & 7;
  int e = tile_e2[wi];
  int m0 = tile_m2[wi];
  int Me = hdr[e];
  int n0 = nt * 128;

  __shared__ __align__(16) char smem[36864];
  char* Asm = smem;              // DEPTH x 4096
  char* Bsm = smem + 12288;      // DEPTH x 8192

  int tid = threadIdx.x, wave = tid >> 6, lane = tid & 63;
  int wm2 = wave >> 1, wn = wave & 1;

  const char* abase = (const char*)Hpack + (size_t)wi * 128 * 4096;
  const char* bbase = (const char*)Bpack2 + (size_t)(e * 8 + nt) * 128 * 8192;
  int aoff = wave * 1024 + lane * 16;              // g = wave (4 groups of 16 rows)
  int off0 = (wave * 2 + 0) * 1024 + lane * 16;
  int off1 = (wave * 2 + 1) * 1024 + lane * 16;

  const int NITER = DFF / 32;  // 128
#pragma unroll
  for (int p = 0; p < DEPTH; ++p) {
    gll16(abase + (size_t)p * 4096 + aoff, Asm + p * 4096 + aoff);
    gll16(bbase + (size_t)p * 8192 + off0, Bsm + p * 8192 + off0);
    gll16(bbase + (size_t)p * 8192 + off1, Bsm + p * 8192 + off1);
  }

  f32x4 acc[2][4];
#pragma unroll
  for (int i = 0; i < 2; ++i)
#pragma unroll
    for (int j = 0; j < 4; ++j) { f32x4 z = {0.f, 0.f, 0.f, 0.f}; acc[i][j] = z; }

  int cur = 0;
  for (int kk = 0; kk < NITER; ++kk) {
    asm volatile("s_waitcnt vmcnt(6)" ::: "memory");   // iter kk's 3 loads landed
    __builtin_amdgcn_s_barrier();
    const char* ab = Asm + cur * 4096;
    const char* bb = Bsm + cur * 8192;
    bf16x8 af[2], bfv[4];
#pragma unroll
    for (int i = 0; i < 2; ++i)
      af[i] = *(const bf16x8*)(ab + (wm2 * 2 + i) * 1024 + lane * 16);
#pragma unroll
    for (int j = 0; j < 4; ++j)
      bfv[j] = *(const bf16x8*)(bb + (wn * 4 + j) * 1024 + lane * 16);
    asm volatile("s_waitcnt lgkmcnt(0)" ::: "memory");
    __builtin_amdgcn_s_barrier();
    int nx = kk + DEPTH;
    if (nx > NITER - 1) nx = NITER - 1;
    char* ad = Asm + cur * 4096;
    char* bd = Bsm + cur * 8192;
    gll16(abase + (size_t)nx * 4096 + aoff, ad + aoff);
    gll16(bbase + (size_t)nx * 8192 + off0, bd + off0);
    gll16(bbase + (size_t)nx * 8192 + off1, bd + off1);
#pragma unroll
    for (int i = 0; i < 2; ++i)
#pragma unroll
      for (int j = 0; j < 4; ++j)
        acc[i][j] = __builtin_amdgcn_mfma_f32_16x16x32_bf16(af[i], bfv[j], acc[i][j], 0, 0, 0);
    cur = (cur == DEPTH - 1) ? 0 : cur + 1;
  }

  int quad = lane >> 4, col_l = lane & 15;
#pragma unroll
  for (int i = 0; i < 2; ++i) {
    int rbase = m0 + wm2 * 32 + i * 16 + quad * 4;
#pragma unroll
    for (int j = 0; j < 4; ++j) {
      int col = n0 + wn * 64 + j * 16 + col_l;
      float bb = b2[(size_t)e * D_IN + col];
#pragma unroll
      for (int r = 0; r < 4; ++r) {
        int rr = rbase + r;
        if (rr < Me) {
          int token = perm[e * N_TOK + rr];
          out[(size_t)token * D_IN + col] = acc[i][j][r] + bb;
        }
      }
    }
  }
}

// ---------- launch ----------
extern "C" void kernel_launch(void* const* d_in, const int* in_sizes, int n_in,
                              void* d_out, int out_size, void* d_ws, size_t ws_size,
                              hipStream_t stream) {
  const float* x  = (const float*)d_in[0];
  const float* gW = (const float*)d_in[1];
  const float* gb = (const float*)d_in[2];
  const float* W1 = (const float*)d_in[3];
  const float* b1 = (const float*)d_in[4];
  const float* W2 = (const float*)d_in[5];
  const float* b2 = (const float*)d_in[6];
  float* out = (float*)d_out;

  char* ws = (char*)d_ws;
  int* hdr     = (int*)ws;                 // counts[8], offsets[9], nt1, nt2
  int* tile_e  = (int*)(ws + 4096);
  int* tile_m  = (int*)(ws + 4608);
  int* sub0    = (int*)(ws + 5120);
  int* tile_e2 = (int*)(ws + 5632);
  int* tile_m2 = (int*)(ws + 6656);
  int* perm    = (int*)(ws + 16384);                      // 256 KB
  unsigned short* xbf    = (unsigned short*)(ws + 524288);    // 16 MB (dead after apack)
  unsigned short* Bpack2 = (unsigned short*)(ws + 524288);    // 64 MB (overlays xbf; written after apack)
  unsigned short* Apack  = (unsigned short*)(ws + 69206016);  // 18.6 MB
  unsigned short* Bpack1 = (unsigned short*)(ws + 92274688);  // 64 MB
  unsigned short* Hpack  = (unsigned short*)(ws + 159383552); // 70.8 MB  (end ~230.2 MB)

  hipMemsetAsync(hdr, 0, 256, stream);
  gate_kernel<<<N_TOK / 4, 256, 0, stream>>>(x, gW, gb, xbf, hdr, perm);
  plan_kernel<<<1, 64, 0, stream>>>(hdr, tile_e, tile_m, sub0, tile_e2, tile_m2);
  apack_kernel<<<71 * 4, 256, 0, stream>>>(xbf, hdr, tile_e, tile_m, perm, Apack);
  wpack_kernel<<<NE * 16 * 64, 256, 0, stream>>>(W1, Bpack1, D_IN, DFF, 16, 64);
  wpack_kernel<<<NE * 64 * 16, 256, 0, stream>>>(W2, Bpack2, DFF, D_IN, 64, 16);
  gemm1<<<71 * 32, 256, 0, stream>>>(Apack, Bpack1, b1, hdr, tile_e, tile_m, sub0, Hpack);
  gemm2<<<135 * 8, 256, 0, stream>>>(Hpack, Bpack2, b2, hdr, tile_e2, tile_m2, perm, out);
}

// Round 5
// 570.176 us; speedup vs baseline: 1.4151x; 1.1430x over previous
//
#include <hip/hip_runtime.h>
#include <hip/hip_bf16.h>
#include <cstdint>

// Problem dims
#define N_TOK 8192   // B*T
#define D_IN  1024
#define DFF   4096
#define NE    8
#define DEPTH 3      // K-loop pipeline depth (LDS buffers)

typedef __bf16 bf16x8 __attribute__((ext_vector_type(8)));
typedef float  f32x4  __attribute__((ext_vector_type(4)));

// ---------- helpers ----------
__device__ __forceinline__ unsigned short f2bf(float f) {
  unsigned u = __float_as_uint(f);
  u += 0x7fffu + ((u >> 16) & 1u);   // RNE
  return (unsigned short)(u >> 16);
}

__device__ __forceinline__ void gll16(const void* g, void* l) {
  __builtin_amdgcn_global_load_lds(
      (__attribute__((address_space(1))) void*)g,
      (__attribute__((address_space(3))) void*)l, 16, 0, 0);
}

// ---------- gate: logits (fp64 acc) -> argmax -> top1; also x->bf16. NO atomics ----------
__global__ __launch_bounds__(256) void gate_kernel(
    const float* __restrict__ x, const float* __restrict__ gW,
    const float* __restrict__ gb, unsigned short* __restrict__ xbf,
    int* __restrict__ top1) {
  int wave = threadIdx.x >> 6, lane = threadIdx.x & 63;
  int n = blockIdx.x * 4 + wave;
  const float* xr = x + (size_t)n * D_IN;
  double acc[NE];
#pragma unroll
  for (int e = 0; e < NE; ++e) acc[e] = 0.0;
#pragma unroll
  for (int j = 0; j < 16; ++j) {
    int d = j * 64 + lane;
    float v = xr[d];
    xbf[(size_t)n * D_IN + d] = f2bf(v);
    float4 g0 = *(const float4*)(gW + (size_t)d * 8);
    float4 g1 = *(const float4*)(gW + (size_t)d * 8 + 4);
    acc[0] += (double)v * (double)g0.x;
    acc[1] += (double)v * (double)g0.y;
    acc[2] += (double)v * (double)g0.z;
    acc[3] += (double)v * (double)g0.w;
    acc[4] += (double)v * (double)g1.x;
    acc[5] += (double)v * (double)g1.y;
    acc[6] += (double)v * (double)g1.z;
    acc[7] += (double)v * (double)g1.w;
  }
#pragma unroll
  for (int m = 32; m >= 1; m >>= 1) {
#pragma unroll
    for (int e = 0; e < NE; ++e) acc[e] += __shfl_xor(acc[e], m);
  }
  if (lane == 0) {
    float best = (float)acc[0] + gb[0];
    int be = 0;
#pragma unroll
    for (int e = 1; e < NE; ++e) {
      float lv = (float)acc[e] + gb[e];
      if (lv > best) { best = lv; be = e; }   // strict > => first max (jnp.argmax)
    }
    top1[n] = be;
  }
}

// ---------- build: single block; counts/perm/worklists via LDS atomics ----------
__global__ __launch_bounds__(1024) void build_kernel(
    const int* __restrict__ top1, int* __restrict__ hdr, int* __restrict__ perm,
    int* __restrict__ tile_e, int* __restrict__ tile_m, int* __restrict__ sub0) {
  __shared__ int cnt[NE];
  int tid = threadIdx.x;
  if (tid < NE) cnt[tid] = 0;
  __syncthreads();
  int mye[8], myp[8];
#pragma unroll
  for (int r = 0; r < 8; ++r) {
    int n = r * 1024 + tid;
    int e = top1[n];
    mye[r] = e;
    myp[r] = atomicAdd(&cnt[e], 1);   // LDS atomic; perm index is EXPERT-LOCAL
  }
  __syncthreads();
  if (tid == 0) {
    int o = 0;
    int n1 = 0, n2 = 0;
    for (int e = 0; e < NE; ++e) {
      int Me = cnt[e];
      hdr[e] = Me;
      hdr[8 + e] = o;
      o += Me;
    }
    hdr[16] = o;
    for (int e = 0; e < NE; ++e) {
      int Me = cnt[e];
      int base2 = n2;
      n2 += (Me + 63) >> 6;
      for (int m0 = 0; m0 < Me; m0 += 128) {
        tile_e[n1] = e; tile_m[n1] = m0; sub0[n1] = base2 + (m0 >> 6); ++n1;
      }
    }
    hdr[17] = n1;
    hdr[18] = n2;
  }
  __syncthreads();
#pragma unroll
  for (int r = 0; r < 8; ++r) {
    int n = r * 1024 + tid;
    perm[mye[r] * N_TOK + myp[r]] = n;   // expert-local position (matches all readers)
  }
}

// ---------- A pack: gather perm rows of xbf into gemm1 LDS-fragment order ----------
__global__ __launch_bounds__(256) void apack_kernel(
    const unsigned short* __restrict__ xbf, const int* __restrict__ hdr,
    const int* __restrict__ tile_e, const int* __restrict__ tile_m,
    const int* __restrict__ perm, unsigned short* __restrict__ Apack) {
  int wi = blockIdx.x >> 2;
  if (wi >= hdr[17]) return;
  int q = blockIdx.x & 3;
  int e = tile_e[wi], m0 = tile_m[wi], Me = hdr[e];
  int wave = threadIdx.x >> 6, lane = threadIdx.x & 63;
  int kq = lane >> 4, m = lane & 15;
#pragma unroll
  for (int s = 0; s < 2; ++s) {
    int g = wave * 2 + s;
    int r = m0 + g * 16 + m;
    if (r >= Me) r = Me - 1;
    int token = perm[e * N_TOK + r];
    const char* src = (const char*)xbf + (size_t)token * 2048 + kq * 16;
    char* dst = (char*)Apack + (size_t)wi * 32 * 8192 + g * 1024 + lane * 16;
    for (int kk = 0; kk < 8; ++kk)
      *(int4*)(dst + (size_t)(q * 8 + kk) * 8192) = *(const int4*)(src + (q * 8 + kk) * 64);
  }
}

// ---------- W pack (both weights in one dispatch) ----------
__device__ __forceinline__ void wpack_body(
    const float* __restrict__ src, unsigned short* __restrict__ dst,
    int R, int C, int tiles_r, int tiles_c, int bid) {
  __shared__ unsigned short tile[64][72];
  int tpe = tiles_r * tiles_c;
  int e = bid / tpe;
  int t = bid % tpe;
  int r0 = (t / tiles_c) * 64, c0 = (t % tiles_c) * 64;  // r0: k base, c0: f base
  const float* s = src + (size_t)e * R * C;
  int tr = threadIdx.x >> 4, tc = (threadIdx.x & 15) * 4;
#pragma unroll
  for (int p = 0; p < 4; ++p) {
    int row = r0 + tr + p * 16;  // k
    const float4 v = *(const float4*)(s + (size_t)row * C + c0 + tc);
    tile[tc + 0][tr + p * 16] = f2bf(v.x);
    tile[tc + 1][tr + p * 16] = f2bf(v.y);
    tile[tc + 2][tr + p * 16] = f2bf(v.z);
    tile[tc + 3][tr + p * 16] = f2bf(v.w);
  }
  __syncthreads();
  int nkk = R >> 5, ntc = C >> 7;
#pragma unroll
  for (int u = 0; u < 2; ++u) {
    int c = u * 256 + threadIdx.x;        // 0..511 chunks of 16B
    int kk_l = c >> 8, gg_l = (c >> 6) & 3, kq = (c >> 4) & 3, mm = c & 15;
    int fl = gg_l * 16 + mm;
    int kl = kk_l * 32 + kq * 8;
    int4 val = *(const int4*)&tile[fl][kl];
    int f = c0 + fl;
    int nt = f >> 7, gg = (f >> 4) & 7;
    int kk = (r0 >> 5) + kk_l;
    size_t off = ((((size_t)e * ntc + nt) * nkk + kk) * 8 + gg) * 1024 + (kq * 16 + mm) * 16;
    *(int4*)((char*)dst + off) = val;
  }
}

__global__ __launch_bounds__(256) void wpack_both(
    const float* __restrict__ W1, unsigned short* __restrict__ B1,
    const float* __restrict__ W2, unsigned short* __restrict__ B2) {
  if (blockIdx.x < NE * 16 * 64)
    wpack_body(W1, B1, D_IN, DFF, 16, 64, blockIdx.x);
  else
    wpack_body(W2, B2, DFF, D_IN, 64, 16, blockIdx.x - NE * 16 * 64);
}

// ---------- GEMM1: Hpack = pack(gelu(Xg @ W1 + b1)), pipelined ----------
__global__ __launch_bounds__(256) void gemm1(
    const unsigned short* __restrict__ Apack, const unsigned short* __restrict__ Bpack1,
    const float* __restrict__ b1, const int* __restrict__ hdr,
    const int* __restrict__ tile_e, const int* __restrict__ tile_m,
    const int* __restrict__ sub0, unsigned short* __restrict__ Hpack) {
  int wi = blockIdx.x >> 5;            // 32 n-tiles (DFF/128)
  if (wi >= hdr[17]) return;
  int nt = blockIdx.x & 31;
  int e = tile_e[wi];
  int m0 = tile_m[wi];
  int Me = hdr[e];
  int n0 = nt * 128;

  __shared__ __align__(16) char smem[49152];
  char* Asm = smem;              // DEPTH x 8192
  char* Bsm = smem + 24576;      // DEPTH x 8192

  int tid = threadIdx.x, wave = tid >> 6, lane = tid & 63;
  int wm = wave >> 1, wn = wave & 1;

  const char* abase = (const char*)Apack + (size_t)wi * 32 * 8192;
  const char* bbase = (const char*)Bpack1 + (size_t)(e * 32 + nt) * 32 * 8192;
  int off0 = (wave * 2 + 0) * 1024 + lane * 16;
  int off1 = (wave * 2 + 1) * 1024 + lane * 16;

  const int NITER = D_IN / 32;  // 32
#pragma unroll
  for (int p = 0; p < DEPTH; ++p) {
    gll16(abase + (size_t)p * 8192 + off0, Asm + p * 8192 + off0);
    gll16(abase + (size_t)p * 8192 + off1, Asm + p * 8192 + off1);
    gll16(bbase + (size_t)p * 8192 + off0, Bsm + p * 8192 + off0);
    gll16(bbase + (size_t)p * 8192 + off1, Bsm + p * 8192 + off1);
  }

  f32x4 acc[4][4];
#pragma unroll
  for (int i = 0; i < 4; ++i)
#pragma unroll
    for (int j = 0; j < 4; ++j) { f32x4 z = {0.f, 0.f, 0.f, 0.f}; acc[i][j] = z; }

  int cur = 0;
  for (int kk = 0; kk < NITER; ++kk) {
    asm volatile("s_waitcnt vmcnt(8)" ::: "memory");
    __builtin_amdgcn_s_barrier();
    const char* ab = Asm + cur * 8192;
    const char* bb = Bsm + cur * 8192;
    bf16x8 af[4], bfv[4];
#pragma unroll
    for (int i = 0; i < 4; ++i)
      af[i] = *(const bf16x8*)(ab + (wm * 4 + i) * 1024 + lane * 16);
#pragma unroll
    for (int j = 0; j < 4; ++j)
      bfv[j] = *(const bf16x8*)(bb + (wn * 4 + j) * 1024 + lane * 16);
    asm volatile("s_waitcnt lgkmcnt(0)" ::: "memory");
    __builtin_amdgcn_s_barrier();
    int nx = kk + DEPTH;
    if (nx > NITER - 1) nx = NITER - 1;
    char* ad = Asm + cur * 8192;
    char* bd = Bsm + cur * 8192;
    gll16(abase + (size_t)nx * 8192 + off0, ad + off0);
    gll16(abase + (size_t)nx * 8192 + off1, ad + off1);
    gll16(bbase + (size_t)nx * 8192 + off0, bd + off0);
    gll16(bbase + (size_t)nx * 8192 + off1, bd + off1);
#pragma unroll
    for (int i = 0; i < 4; ++i)
#pragma unroll
      for (int j = 0; j < 4; ++j)
        acc[i][j] = __builtin_amdgcn_mfma_f32_16x16x32_bf16(af[i], bfv[j], acc[i][j], 0, 0, 0);
    cur = (cur == DEPTH - 1) ? 0 : cur + 1;
  }

  // ---- epilogue: gelu+bias -> LDS -> Hpack (gemm2 A-frag order) ----
  asm volatile("s_waitcnt vmcnt(0)" ::: "memory");
  __syncthreads();
  unsigned short* Cl = (unsigned short*)smem;       // 128x128 bf16 = 32 KB
  int quad = lane >> 4, col_l = lane & 15;
#pragma unroll
  for (int i = 0; i < 4; ++i) {
#pragma unroll
    for (int j = 0; j < 4; ++j) {
      int f = n0 + wn * 64 + j * 16 + col_l;
      float bb = b1[(size_t)e * DFF + f];
      int lc = wn * 64 + j * 16 + col_l;
#pragma unroll
      for (int r = 0; r < 4; ++r) {
        int lr = wm * 64 + i * 16 + quad * 4 + r;
        float v = acc[i][j][r] + bb;
        v = 0.5f * v * (1.0f + erff(v * 0.70710678118654752f));  // exact gelu
        Cl[lr * 128 + lc] = f2bf(v);
      }
    }
  }
  __syncthreads();
  int s0 = sub0[wi];
  bool hasB = (m0 + 64 < Me);
#pragma unroll
  for (int u = 0; u < 8; ++u) {
    int c = u * 256 + tid;            // 0..2047 chunks of 16B
    int lr = c >> 4, fc = c & 15;
    int sv = lr >> 6;
    if (sv == 1 && !hasB) continue;
    int4 val = *(const int4*)(Cl + lr * 128 + fc * 8);
    int wi2 = s0 + sv;
    int m2 = lr & 63;
    int gg = m2 >> 4, mm = m2 & 15;
    int kk2 = nt * 4 + (fc >> 2), kq2 = fc & 3;
    *(int4*)((char*)Hpack + ((size_t)wi2 * 128 + kk2) * 4096 + gg * 1024 + (kq2 * 16 + mm) * 16) = val;
  }
}

// ---------- GEMM2: out[token] = Hpack @ W2 + b2, BM=128, pipelined ----------
__global__ __launch_bounds__(256) void gemm2(
    const unsigned short* __restrict__ Hpack, const unsigned short* __restrict__ Bpack2,
    const float* __restrict__ b2, const int* __restrict__ hdr,
    const int* __restrict__ tile_e, const int* __restrict__ tile_m,
    const int* __restrict__ sub0, const int* __restrict__ perm,
    float* __restrict__ out) {
  int wi = blockIdx.x >> 3;            // 8 n-tiles (D/128)
  if (wi >= hdr[17]) return;
  int nt = blockIdx.x & 7;
  int e = tile_e[wi];
  int m0 = tile_m[wi];
  int Me = hdr[e];
  int n0 = nt * 128;
  int s0 = sub0[wi];
  int s1 = (m0 + 64 < Me) ? s0 + 1 : s0;

  __shared__ __align__(16) char smem[49152];
  char* Asm = smem;              // DEPTH x 8192
  char* Bsm = smem + 24576;      // DEPTH x 8192

  int tid = threadIdx.x, wave = tid >> 6, lane = tid & 63;
  int wm = wave >> 1, wn = wave & 1;

  // A: two row-groups per wave; rows 0..63 from subtile s0, 64..127 from s1
  const char* abase_s[2];
  int agl[2];
  int off_s[2];
#pragma unroll
  for (int s = 0; s < 2; ++s) {
    int g = wave * 2 + s;                    // 0..7, 16 rows each
    int sv = g >> 2;
    abase_s[s] = (const char*)Hpack + (size_t)((sv ? s1 : s0) * 128) * 4096;
    agl[s] = (g & 3) * 1024 + lane * 16;
    off_s[s] = g * 1024 + lane * 16;
  }
  const char* bbase = (const char*)Bpack2 + (size_t)(e * 8 + nt) * 128 * 8192;

  const int NITER = DFF / 32;  // 128
#pragma unroll
  for (int p = 0; p < DEPTH; ++p) {
    gll16(abase_s[0] + (size_t)p * 4096 + agl[0], Asm + p * 8192 + off_s[0]);
    gll16(abase_s[1] + (size_t)p * 4096 + agl[1], Asm + p * 8192 + off_s[1]);
    gll16(bbase + (size_t)p * 8192 + off_s[0], Bsm + p * 8192 + off_s[0]);
    gll16(bbase + (size_t)p * 8192 + off_s[1], Bsm + p * 8192 + off_s[1]);
  }

  f32x4 acc[4][4];
#pragma unroll
  for (int i = 0; i < 4; ++i)
#pragma unroll
    for (int j = 0; j < 4; ++j) { f32x4 z = {0.f, 0.f, 0.f, 0.f}; acc[i][j] = z; }

  int cur = 0;
  for (int kk = 0; kk < NITER; ++kk) {
    asm volatile("s_waitcnt vmcnt(8)" ::: "memory");
    __builtin_amdgcn_s_barrier();
    const char* ab = Asm + cur * 8192;
    const char* bb = Bsm + cur * 8192;
    bf16x8 af[4], bfv[4];
#pragma unroll
    for (int i = 0; i < 4; ++i)
      af[i] = *(const bf16x8*)(ab + (wm * 4 + i) * 1024 + lane * 16);
#pragma unroll
    for (int j = 0; j < 4; ++j)
      bfv[j] = *(const bf16x8*)(bb + (wn * 4 + j) * 1024 + lane * 16);
    asm volatile("s_waitcnt lgkmcnt(0)" ::: "memory");
    __builtin_amdgcn_s_barrier();
    int nx = kk + DEPTH;
    if (nx > NITER - 1) nx = NITER - 1;
    char* ad = Asm + cur * 8192;
    char* bd = Bsm + cur * 8192;
    gll16(abase_s[0] + (size_t)nx * 4096 + agl[0], ad + off_s[0]);
    gll16(abase_s[1] + (size_t)nx * 4096 + agl[1], ad + off_s[1]);
    gll16(bbase + (size_t)nx * 8192 + off_s[0], bd + off_s[0]);
    gll16(bbase + (size_t)nx * 8192 + off_s[1], bd + off_s[1]);
#pragma unroll
    for (int i = 0; i < 4; ++i)
#pragma unroll
      for (int j = 0; j < 4; ++j)
        acc[i][j] = __builtin_amdgcn_mfma_f32_16x16x32_bf16(af[i], bfv[j], acc[i][j], 0, 0, 0);
    cur = (cur == DEPTH - 1) ? 0 : cur + 1;
  }

  int quad = lane >> 4, col_l = lane & 15;
#pragma unroll
  for (int i = 0; i < 4; ++i) {
    int rbase = m0 + wm * 64 + i * 16 + quad * 4;
#pragma unroll
    for (int j = 0; j < 4; ++j) {
      int col = n0 + wn * 64 + j * 16 + col_l;
      float bb = b2[(size_t)e * D_IN + col];
#pragma unroll
      for (int r = 0; r < 4; ++r) {
        int rr = rbase + r;
        if (rr < Me) {
          int token = perm[e * N_TOK + rr];
          out[(size_t)token * D_IN + col] = acc[i][j][r] + bb;
        }
      }
    }
  }
}

// ---------- launch ----------
extern "C" void kernel_launch(void* const* d_in, const int* in_sizes, int n_in,
                              void* d_out, int out_size, void* d_ws, size_t ws_size,
                              hipStream_t stream) {
  const float* x  = (const float*)d_in[0];
  const float* gW = (const float*)d_in[1];
  const float* gb = (const float*)d_in[2];
  const float* W1 = (const float*)d_in[3];
  const float* b1 = (const float*)d_in[4];
  const float* W2 = (const float*)d_in[5];
  const float* b2 = (const float*)d_in[6];
  float* out = (float*)d_out;

  char* ws = (char*)d_ws;
  int* hdr     = (int*)ws;                 // counts[8], offsets[9], nt1, nt2
  int* tile_e  = (int*)(ws + 4096);
  int* tile_m  = (int*)(ws + 4608);
  int* sub0    = (int*)(ws + 5120);
  int* top1    = (int*)(ws + 8192);                       // 32 KB
  int* perm    = (int*)(ws + 65536);                      // 256 KB
  unsigned short* xbf    = (unsigned short*)(ws + 524288);    // 16 MB (dead after apack)
  unsigned short* Bpack2 = (unsigned short*)(ws + 524288);    // 64 MB overlay; written after apack (same-stream order)
  unsigned short* Apack  = (unsigned short*)(ws + 69206016);  // 18.6 MB
  unsigned short* Bpack1 = (unsigned short*)(ws + 92274688);  // 64 MB
  unsigned short* Hpack  = (unsigned short*)(ws + 159383552); // 70.8 MB (end ~230.2 MB, = R3 proven size)

  gate_kernel<<<N_TOK / 4, 256, 0, stream>>>(x, gW, gb, xbf, top1);
  build_kernel<<<1, 1024, 0, stream>>>(top1, hdr, perm, tile_e, tile_m, sub0);
  apack_kernel<<<71 * 4, 256, 0, stream>>>(xbf, hdr, tile_e, tile_m, perm, Apack);
  wpack_both<<<NE * 16 * 64 + NE * 64 * 16, 256, 0, stream>>>(W1, Bpack1, W2, Bpack2);
  gemm1<<<71 * 32, 256, 0, stream>>>(Apack, Bpack1, b1, hdr, tile_e, tile_m, sub0, Hpack);
  gemm2<<<71 * 8, 256, 0, stream>>>(Hpack, Bpack2, b2, hdr, tile_e, tile_m, sub0, perm, out);
}